// Round 1
// baseline (608.309 us; speedup 1.0000x reference)
//
#include <hip/hip_runtime.h>

#define HID 128
#define LN_EPS 1e-5f

// ---------------- CSR build ----------------

__global__ void zero_ints_kernel(int* __restrict__ p, int n) {
  int i = blockIdx.x * blockDim.x + threadIdx.x;
  if (i < n) p[i] = 0;
}

__global__ void deg_count_kernel(const int* __restrict__ dst, int E, int* __restrict__ deg) {
  int e = blockIdx.x * blockDim.x + threadIdx.x;
  if (e < E) atomicAdd(&deg[dst[e]], 1);
}

__global__ __launch_bounds__(1024) void scan_kernel(const int* __restrict__ deg,
                                                    int* __restrict__ roff,
                                                    int* __restrict__ cur, int n) {
  __shared__ int wtot[16];
  __shared__ int sbase[16];
  __shared__ int s_total;
  __shared__ int s_carry;
  int t = threadIdx.x, lane = t & 63, wid = t >> 6;
  if (t == 0) s_carry = 0;
  __syncthreads();
  for (int base = 0; base < n; base += 1024) {
    int i = base + t;
    int v = (i < n) ? deg[i] : 0;
    int x = v;
    #pragma unroll
    for (int off = 1; off < 64; off <<= 1) {
      int u = __shfl_up(x, off, 64);
      if (lane >= off) x += u;
    }
    if (lane == 63) wtot[wid] = x;
    __syncthreads();
    if (wid == 0) {
      int tv = (lane < 16) ? wtot[lane] : 0;
      int y = tv;
      #pragma unroll
      for (int off = 1; off < 16; off <<= 1) {
        int u = __shfl_up(y, off, 64);
        if (lane >= off) y += u;
      }
      if (lane < 16) sbase[lane] = y - tv;
      if (lane == 15) s_total = y;
    }
    __syncthreads();
    int excl = s_carry + sbase[wid] + x - v;
    if (i < n) { roff[i] = excl; cur[i] = excl; }
    __syncthreads();
    if (t == 0) s_carry += s_total;
    __syncthreads();
  }
  if (t == 0) roff[n] = s_carry;
}

__global__ void fill_csr_kernel(const int* __restrict__ src, const int* __restrict__ dst,
                                int E, int* __restrict__ cur, int* __restrict__ col) {
  int e = blockIdx.x * blockDim.x + threadIdx.x;
  if (e < E) {
    int d = dst[e];
    int p = atomicAdd(&cur[d], 1);
    col[p] = src[e];
  }
}

__global__ void dinv_kernel(const int* __restrict__ deg, float* __restrict__ dinv, int n) {
  int i = blockIdx.x * blockDim.x + threadIdx.x;
  if (i < n) dinv[i] = rsqrtf((float)(deg[i] + 1));  // +1 self loop, always >= 1
}

// ---------------- GEMM: Y[M,128] = X[M,128] @ W[128,128], epilogue (acc+bias)*dinv ----------------
// 64-row tile per block, 256 threads, each thread 4 rows x 8 cols.

__global__ __launch_bounds__(256) void gemm128_kernel(
    const float* __restrict__ X, const float* __restrict__ W,
    const float* __restrict__ bias, const float* __restrict__ dinv,
    float* __restrict__ Y, int M) {
  __shared__ __align__(16) float xs[HID * 64];  // [k][row], transposed
  int t = threadIdx.x;
  int row0 = blockIdx.x * 64;

  {  // stage x transposed
    int row = t & 63;
    int kq = t >> 6;  // 0..3
    bool valid = (row0 + row) < M;
    const float* xp = X + (size_t)(row0 + row) * HID;
    #pragma unroll
    for (int j = 0; j < 8; ++j) {
      int k0 = kq * 32 + j * 4;
      float4 v = make_float4(0.f, 0.f, 0.f, 0.f);
      if (valid) v = *reinterpret_cast<const float4*>(xp + k0);
      xs[(k0 + 0) * 64 + row] = v.x;
      xs[(k0 + 1) * 64 + row] = v.y;
      xs[(k0 + 2) * 64 + row] = v.z;
      xs[(k0 + 3) * 64 + row] = v.w;
    }
  }
  __syncthreads();

  int c = t & 15;   // col group: cols c*8..c*8+7
  int rg = t >> 4;  // row group: rows rg*4..rg*4+3
  float acc[4][8];
  #pragma unroll
  for (int i = 0; i < 4; ++i)
    #pragma unroll
    for (int j = 0; j < 8; ++j) acc[i][j] = 0.f;

  const float4* W4 = reinterpret_cast<const float4*>(W);
  #pragma unroll 8
  for (int k = 0; k < HID; ++k) {
    float4 xv = *reinterpret_cast<const float4*>(&xs[k * 64 + (rg << 2)]);
    float4 w0 = W4[k * 32 + (c << 1)];
    float4 w1 = W4[k * 32 + (c << 1) + 1];
    float xr[4] = {xv.x, xv.y, xv.z, xv.w};
    float wr[8] = {w0.x, w0.y, w0.z, w0.w, w1.x, w1.y, w1.z, w1.w};
    #pragma unroll
    for (int i = 0; i < 4; ++i)
      #pragma unroll
      for (int j = 0; j < 8; ++j)
        acc[i][j] = fmaf(xr[i], wr[j], acc[i][j]);
  }

  float bv[8];
  #pragma unroll
  for (int j = 0; j < 8; ++j) bv[j] = bias ? bias[c * 8 + j] : 0.f;

  #pragma unroll
  for (int i = 0; i < 4; ++i) {
    int row = row0 + rg * 4 + i;
    if (row < M) {
      float s = dinv ? dinv[row] : 1.f;
      float4 o0, o1;
      o0.x = (acc[i][0] + bv[0]) * s;
      o0.y = (acc[i][1] + bv[1]) * s;
      o0.z = (acc[i][2] + bv[2]) * s;
      o0.w = (acc[i][3] + bv[3]) * s;
      o1.x = (acc[i][4] + bv[4]) * s;
      o1.y = (acc[i][5] + bv[5]) * s;
      o1.z = (acc[i][6] + bv[6]) * s;
      o1.w = (acc[i][7] + bv[7]) * s;
      float* yp = Y + (size_t)row * HID + c * 8;
      *reinterpret_cast<float4*>(yp) = o0;
      *reinterpret_cast<float4*>(yp + 4) = o1;
    }
  }
}

// ---------------- aggregation + LayerNorm + ReLU ----------------
// One block (128 threads) per node; pull over CSR; LN across the 128 channels.
// mode 0: y = val, accum = val;  mode 1: accum += val;  mode 2: y = val.

__global__ __launch_bounds__(128) void agg_ln_kernel(
    const float* __restrict__ G, const int* __restrict__ roff, const int* __restrict__ col,
    const float* __restrict__ dinv, const float* __restrict__ bias,
    const float* __restrict__ lng, const float* __restrict__ lnb,
    float* __restrict__ y, float* __restrict__ accum, int mode) {
  int v = blockIdx.x, t = threadIdx.x;
  __shared__ int sc[128];
  __shared__ float red[4];

  float a = G[(size_t)v * HID + t];  // self loop (g already dinv-scaled)
  int lo = roff[v], hi = roff[v + 1];
  for (int base = lo; base < hi; base += 128) {
    int nn = hi - base;
    if (nn > 128) nn = 128;
    __syncthreads();
    if (t < nn) sc[t] = col[base + t];
    __syncthreads();
    for (int j = 0; j < nn; ++j) a += G[(size_t)sc[j] * HID + t];
  }
  a = a * dinv[v] + bias[t];

  float s1 = a, s2 = a * a;
  #pragma unroll
  for (int off = 32; off >= 1; off >>= 1) {
    s1 += __shfl_xor(s1, off, 64);
    s2 += __shfl_xor(s2, off, 64);
  }
  int wid = t >> 6, lane = t & 63;
  if (lane == 0) { red[wid * 2] = s1; red[wid * 2 + 1] = s2; }
  __syncthreads();
  float sum = red[0] + red[2], ssq = red[1] + red[3];
  float mu = sum * (1.f / HID);
  float var = ssq * (1.f / HID) - mu * mu;
  float inv = rsqrtf(fmaxf(var, 0.f) + LN_EPS);
  float yv = fmaxf((a - mu) * inv * lng[t] + lnb[t], 0.f);

  size_t idx = (size_t)v * HID + t;
  if (mode == 0) { y[idx] = yv; accum[idx] = yv; }
  else if (mode == 1) { accum[idx] += yv; }
  else { y[idx] = yv; }
}

// ---------------- pooling + post MLP ----------------

__device__ inline int lower_bound_i(const int* a, int n, int key) {
  int lo = 0, hi = n;
  while (lo < hi) { int m = (lo + hi) >> 1; if (a[m] < key) lo = m + 1; else hi = m; }
  return lo;
}

__global__ __launch_bounds__(128) void pool_post_kernel(
    const float* __restrict__ Yl, const int* __restrict__ batch, int n,
    const float* __restrict__ Wp, const float* __restrict__ bp,
    float* __restrict__ out, int n_out) {
  int g = blockIdx.x, t = threadIdx.x;
  int lo = lower_bound_i(batch, n, g);
  int hi = lower_bound_i(batch, n, g + 1);
  float acc = 0.f;
  for (int i = lo; i < hi; ++i) acc += Yl[(size_t)i * HID + t];
  __shared__ float ls[HID];
  ls[t] = acc;
  __syncthreads();
  if (t < n_out) {
    float o = bp[t];
    #pragma unroll 8
    for (int k = 0; k < HID; ++k) o = fmaf(ls[k], Wp[k * n_out + t], o);
    out[g * n_out + t] = o;
  }
}

// ---------------- launch ----------------

extern "C" void kernel_launch(void* const* d_in, const int* in_sizes, int n_in,
                              void* d_out, int out_size, void* d_ws, size_t ws_size,
                              hipStream_t stream) {
  const float* x      = (const float*)d_in[0];
  const int*   ei     = (const int*)d_in[1];
  const int*   batch  = (const int*)d_in[2];
  const float* W_pre  = (const float*)d_in[3];
  const float* b_pre  = (const float*)d_in[4];
  const float* conv_W = (const float*)d_in[5];
  const float* conv_b = (const float*)d_in[6];
  const float* ln_g   = (const float*)d_in[7];
  const float* ln_b   = (const float*)d_in[8];
  const float* W_post = (const float*)d_in[9];
  const float* b_post = (const float*)d_in[10];
  float* out = (float*)d_out;

  const int N = in_sizes[2];          // 50000
  const int E = in_sizes[1] / 2;      // 600000
  const int OUT_DIM = 10;
  const int NG = out_size / OUT_DIM;  // 512

  // workspace carve
  float* B1  = (float*)d_ws;               // [N,128] h0 / y0 / y_last
  float* G   = B1 + (size_t)N * HID;       // [N,128] scaled conv-GEMM output
  float* ACC = G  + (size_t)N * HID;       // [N,128] running sum of cell outputs
  int* deg   = (int*)(ACC + (size_t)N * HID);
  int* roff  = deg + N;        // N+1
  int* cur   = roff + N + 1;   // N
  int* col   = cur + N;        // E
  float* dinv = (float*)(col + E);

  const int* srcp = ei;
  const int* dstp = ei + E;

  int nb256 = (N + 255) / 256;
  int eb256 = (E + 255) / 256;
  int gemm_grid = (N + 63) / 64;

  // CSR + dinv (same for all cells)
  zero_ints_kernel<<<nb256, 256, 0, stream>>>(deg, N);
  deg_count_kernel<<<eb256, 256, 0, stream>>>(dstp, E, deg);
  scan_kernel<<<1, 1024, 0, stream>>>(deg, roff, cur, N);
  fill_csr_kernel<<<eb256, 256, 0, stream>>>(srcp, dstp, E, cur, col);
  dinv_kernel<<<nb256, 256, 0, stream>>>(deg, dinv, N);

  // pre MLP: B1 = x @ W_pre + b_pre
  gemm128_kernel<<<gemm_grid, 256, 0, stream>>>(x, W_pre, b_pre, nullptr, B1, N);

  // cell 0: in B1(h0) -> G -> y0 to B1, ACC = y0
  gemm128_kernel<<<gemm_grid, 256, 0, stream>>>(B1, conv_W + 0 * HID * HID, nullptr, dinv, G, N);
  agg_ln_kernel<<<N, 128, 0, stream>>>(G, roff, col, dinv, conv_b + 0 * HID,
                                       ln_g + 0 * HID, ln_b + 0 * HID, B1, ACC, 0);
  // cell 1: in B1(y0) -> G -> ACC += y1
  gemm128_kernel<<<gemm_grid, 256, 0, stream>>>(B1, conv_W + 1 * HID * HID, nullptr, dinv, G, N);
  agg_ln_kernel<<<N, 128, 0, stream>>>(G, roff, col, dinv, conv_b + 1 * HID,
                                       ln_g + 1 * HID, ln_b + 1 * HID, nullptr, ACC, 1);
  // cell 2: in ACC(n0+n1) -> G -> ACC += y2
  gemm128_kernel<<<gemm_grid, 256, 0, stream>>>(ACC, conv_W + 2 * HID * HID, nullptr, dinv, G, N);
  agg_ln_kernel<<<N, 128, 0, stream>>>(G, roff, col, dinv, conv_b + 2 * HID,
                                       ln_g + 2 * HID, ln_b + 2 * HID, nullptr, ACC, 1);
  // cell 3: in ACC(n0+n1+s2l) -> G -> y_last to B1
  gemm128_kernel<<<gemm_grid, 256, 0, stream>>>(ACC, conv_W + 3 * HID * HID, nullptr, dinv, G, N);
  agg_ln_kernel<<<N, 128, 0, stream>>>(G, roff, col, dinv, conv_b + 3 * HID,
                                       ln_g + 3 * HID, ln_b + 3 * HID, B1, nullptr, 2);

  // pooling + post MLP
  pool_post_kernel<<<NG, 128, 0, stream>>>(B1, batch, N, W_post, b_post, out, OUT_DIM);
}

// Round 2
// 373.382 us; speedup vs baseline: 1.6292x; 1.6292x over previous
//
#include <hip/hip_runtime.h>

#define HID 128
#define LN_EPS 1e-5f

using f32x4 = __attribute__((ext_vector_type(4))) float;
using s16x8 = __attribute__((ext_vector_type(8))) short;

__device__ inline float bl2f(unsigned u) { u <<= 16; return __builtin_bit_cast(float, u); }
__device__ inline float bh2f(unsigned u) { u &= 0xffff0000u; return __builtin_bit_cast(float, u); }
__device__ inline unsigned f2b_bits(float f) {
  unsigned u = __builtin_bit_cast(unsigned, f);
  return (u + 0x7fffu + ((u >> 16) & 1u)) >> 16;  // RNE
}
__device__ inline short f2b(float f) { return (short)f2b_bits(f); }
__device__ inline unsigned pack2(float a, float b) { return f2b_bits(a) | (f2b_bits(b) << 16); }

// ---------------- weight prep: Wt[w][n][k] = bf16(W[w][k][n]) ----------------

__global__ __launch_bounds__(64) void prep_w_kernel(const float* __restrict__ W_pre,
                                                    const float* __restrict__ conv_W,
                                                    short* __restrict__ Wt) {
  int b = blockIdx.x;            // 0..639
  int w = b >> 7, n = b & 127;
  const float* W = (w == 0) ? W_pre : conv_W + (size_t)(w - 1) * HID * HID;
  int t = threadIdx.x;           // k = 2t, 2t+1
  float f0 = W[(2 * t) * HID + n];
  float f1 = W[(2 * t + 1) * HID + n];
  ((unsigned*)Wt)[(size_t)(w * HID + n) * 64 + t] = pack2(f0, f1);
}

// ---------------- CSR build ----------------

__global__ void zero_ints_kernel(int* __restrict__ p, int n) {
  int i = blockIdx.x * blockDim.x + threadIdx.x;
  if (i < n) p[i] = 0;
}

__global__ void deg_count_kernel(const int* __restrict__ dst, int E, int* __restrict__ deg) {
  int e = blockIdx.x * blockDim.x + threadIdx.x;
  if (e < E) atomicAdd(&deg[dst[e]], 1);
}

__global__ __launch_bounds__(1024) void scan_kernel(const int* __restrict__ deg,
                                                    int* __restrict__ roff,
                                                    int* __restrict__ cur, int n) {
  __shared__ int wtot[16];
  __shared__ int sbase[16];
  __shared__ int s_total;
  __shared__ int s_carry;
  int t = threadIdx.x, lane = t & 63, wid = t >> 6;
  if (t == 0) s_carry = 0;
  __syncthreads();
  for (int base = 0; base < n; base += 4096) {
    int i = base + t * 4;
    int d0 = (i + 0 < n) ? deg[i + 0] : 0;
    int d1 = (i + 1 < n) ? deg[i + 1] : 0;
    int d2 = (i + 2 < n) ? deg[i + 2] : 0;
    int d3 = (i + 3 < n) ? deg[i + 3] : 0;
    int s = d0 + d1 + d2 + d3;
    int x = s;
    #pragma unroll
    for (int off = 1; off < 64; off <<= 1) {
      int u = __shfl_up(x, off, 64);
      if (lane >= off) x += u;
    }
    if (lane == 63) wtot[wid] = x;
    __syncthreads();
    if (wid == 0) {
      int tv = (lane < 16) ? wtot[lane] : 0;
      int y = tv;
      #pragma unroll
      for (int off = 1; off < 16; off <<= 1) {
        int u = __shfl_up(y, off, 64);
        if (lane >= off) y += u;
      }
      if (lane < 16) sbase[lane] = y - tv;
      if (lane == 15) s_total = y;
    }
    __syncthreads();
    int excl = s_carry + sbase[wid] + x - s;
    if (i + 0 < n) { roff[i + 0] = excl; cur[i + 0] = excl; } excl += d0;
    if (i + 1 < n) { roff[i + 1] = excl; cur[i + 1] = excl; } excl += d1;
    if (i + 2 < n) { roff[i + 2] = excl; cur[i + 2] = excl; } excl += d2;
    if (i + 3 < n) { roff[i + 3] = excl; cur[i + 3] = excl; }
    __syncthreads();
    if (t == 0) s_carry += s_total;
    __syncthreads();
  }
  if (t == 0) roff[n] = s_carry;
}

__global__ void fill_csr_kernel(const int* __restrict__ src, const int* __restrict__ dst,
                                int E, int* __restrict__ cur, int* __restrict__ col) {
  int e = blockIdx.x * blockDim.x + threadIdx.x;
  if (e < E) {
    int d = dst[e];
    int p = atomicAdd(&cur[d], 1);
    col[p] = src[e];
  }
}

__global__ void dinv_kernel(const int* __restrict__ deg, float* __restrict__ dinv, int n) {
  int i = blockIdx.x * blockDim.x + threadIdx.x;
  if (i < n) dinv[i] = rsqrtf((float)(deg[i] + 1));
}

// ---------------- MFMA GEMM: Y[M,128](bf16) = X[M,128] @ Wt^T, epi (acc+bias)*dinv ----------------
// 128-row tile per block, 4 waves; each wave 32 rows x 128 cols via 2x8 16x16x32 frags.

template<bool AF32>
__global__ __launch_bounds__(256) void gemm_mfma_kernel(
    const void* __restrict__ Xv, const short* __restrict__ Wt,
    const float* __restrict__ bias, const float* __restrict__ dinv,
    short* __restrict__ Y, int M) {
  __shared__ short lds[4 * 32 * HID];  // 32 KB
  int t = threadIdx.x;
  int wave = t >> 6, l = t & 63;
  int lg = l >> 4, lr = l & 15;
  int mb = blockIdx.x * 128 + wave * 32;

  const f32x4 z4 = {0.f, 0.f, 0.f, 0.f};
  f32x4 acc[2][8];
  #pragma unroll
  for (int i = 0; i < 2; ++i)
    #pragma unroll
    for (int j = 0; j < 8; ++j) acc[i][j] = z4;

  const short* Xb = (const short*)Xv;
  const float* Xf = (const float*)Xv;

  #pragma unroll
  for (int kk = 0; kk < 4; ++kk) {
    int k0 = kk * 32 + lg * 8;
    s16x8 a[2];
    #pragma unroll
    for (int mf = 0; mf < 2; ++mf) {
      int row = mb + mf * 16 + lr;
      s16x8 av = {0, 0, 0, 0, 0, 0, 0, 0};
      if (row < M) {
        if constexpr (AF32) {
          const float4* p = (const float4*)(Xf + (size_t)row * HID + k0);
          float4 x0 = p[0], x1 = p[1];
          av[0] = f2b(x0.x); av[1] = f2b(x0.y); av[2] = f2b(x0.z); av[3] = f2b(x0.w);
          av[4] = f2b(x1.x); av[5] = f2b(x1.y); av[6] = f2b(x1.z); av[7] = f2b(x1.w);
        } else {
          av = *(const s16x8*)(Xb + (size_t)row * HID + k0);
        }
      }
      a[mf] = av;
    }
    #pragma unroll
    for (int nf = 0; nf < 8; ++nf) {
      s16x8 b = *(const s16x8*)(Wt + (size_t)(nf * 16 + lr) * HID + k0);
      acc[0][nf] = __builtin_amdgcn_mfma_f32_16x16x32_bf16(a[0], b, acc[0][nf], 0, 0, 0);
      acc[1][nf] = __builtin_amdgcn_mfma_f32_16x16x32_bf16(a[1], b, acc[1][nf], 0, 0, 0);
    }
  }

  float bv[8];
  #pragma unroll
  for (int nf = 0; nf < 8; ++nf) bv[nf] = bias ? bias[nf * 16 + lr] : 0.f;

  short* wsl = lds + wave * 32 * HID;
  #pragma unroll
  for (int mf = 0; mf < 2; ++mf) {
    #pragma unroll
    for (int r = 0; r < 4; ++r) {
      int ri = mf * 16 + lg * 4 + r;
      int row = mb + ri;
      float dv = 1.f;
      if (dinv && row < M) dv = dinv[row];
      #pragma unroll
      for (int nf = 0; nf < 8; ++nf) {
        float v = (acc[mf][nf][r] + bv[nf]) * dv;
        wsl[ri * HID + nf * 16 + lr] = f2b(v);
      }
    }
  }
  __syncthreads();

  #pragma unroll
  for (int it = 0; it < 8; ++it) {
    int ro = it * 4 + lg;
    int row = mb + ro;
    s16x8 v = *(const s16x8*)(wsl + it * 512 + l * 8);
    if (row < M) *(s16x8*)(Y + (size_t)row * HID + lr * 8) = v;
  }
}

// ---------------- aggregation + LayerNorm + ReLU: one wave per node ----------------
// mode 0: y = val, accum = val;  mode 1: accum += val;  mode 2: y = val.

__global__ __launch_bounds__(256) void agg_ln_kernel(
    const short* __restrict__ G, const int* __restrict__ roff, const int* __restrict__ col,
    const float* __restrict__ dinv, const float* __restrict__ bias,
    const float* __restrict__ lng, const float* __restrict__ lnb,
    short* __restrict__ y, float* __restrict__ accum, int N, int mode) {
  int wave = threadIdx.x >> 6, l = threadIdx.x & 63;
  int v = blockIdx.x * 4 + wave;
  if (v >= N) return;

  const unsigned* GR = (const unsigned*)G;  // row v at GR[v*64 + l] -> channels 2l, 2l+1
  unsigned us = GR[(size_t)v * 64 + l];
  float a0 = bl2f(us), a1 = bh2f(us);

  int lo = roff[v], hi = roff[v + 1];
  int j = lo;
  for (; j + 3 < hi; j += 4) {
    int s0 = col[j], s1 = col[j + 1], s2 = col[j + 2], s3 = col[j + 3];
    unsigned u0 = GR[(size_t)s0 * 64 + l];
    unsigned u1 = GR[(size_t)s1 * 64 + l];
    unsigned u2 = GR[(size_t)s2 * 64 + l];
    unsigned u3 = GR[(size_t)s3 * 64 + l];
    a0 += bl2f(u0) + bl2f(u1) + bl2f(u2) + bl2f(u3);
    a1 += bh2f(u0) + bh2f(u1) + bh2f(u2) + bh2f(u3);
  }
  for (; j < hi; ++j) {
    unsigned u = GR[(size_t)col[j] * 64 + l];
    a0 += bl2f(u); a1 += bh2f(u);
  }

  float d = dinv[v];
  float2 bc = *(const float2*)(bias + 2 * l);
  a0 = a0 * d + bc.x;
  a1 = a1 * d + bc.y;

  float s1s = a0 + a1, s2s = a0 * a0 + a1 * a1;
  #pragma unroll
  for (int off = 32; off >= 1; off >>= 1) {
    s1s += __shfl_xor(s1s, off, 64);
    s2s += __shfl_xor(s2s, off, 64);
  }
  float mu = s1s * (1.f / HID);
  float var = s2s * (1.f / HID) - mu * mu;
  float inv = rsqrtf(fmaxf(var, 0.f) + LN_EPS);

  float2 gg = *(const float2*)(lng + 2 * l);
  float2 bb = *(const float2*)(lnb + 2 * l);
  float y0 = fmaxf((a0 - mu) * inv * gg.x + bb.x, 0.f);
  float y1 = fmaxf((a1 - mu) * inv * gg.y + bb.y, 0.f);

  size_t idx = (size_t)v * 64 + l;
  if (mode == 0) {
    ((unsigned*)y)[idx] = pack2(y0, y1);
    ((float2*)accum)[idx] = make_float2(y0, y1);
  } else if (mode == 1) {
    float2 o = ((float2*)accum)[idx];
    ((float2*)accum)[idx] = make_float2(o.x + y0, o.y + y1);
  } else {
    ((unsigned*)y)[idx] = pack2(y0, y1);
  }
}

// ---------------- pooling + post MLP ----------------

__device__ inline int lower_bound_i(const int* a, int n, int key) {
  int lo = 0, hi = n;
  while (lo < hi) { int m = (lo + hi) >> 1; if (a[m] < key) lo = m + 1; else hi = m; }
  return lo;
}

__global__ __launch_bounds__(128) void pool_post_kernel(
    const short* __restrict__ Yl, const int* __restrict__ batch, int n,
    const float* __restrict__ Wp, const float* __restrict__ bp,
    float* __restrict__ out, int n_out) {
  int g = blockIdx.x, t = threadIdx.x;
  int wave = t >> 6, l = t & 63;
  int lo = lower_bound_i(batch, n, g);
  int hi = lower_bound_i(batch, n, g + 1);
  const unsigned* YR = (const unsigned*)Yl;
  float a0 = 0.f, a1 = 0.f;
  for (int i = lo + wave; i < hi; i += 2) {
    unsigned u = YR[(size_t)i * 64 + l];
    a0 += bl2f(u); a1 += bh2f(u);
  }
  __shared__ float ls[2][HID];
  ls[wave][2 * l] = a0;
  ls[wave][2 * l + 1] = a1;
  __syncthreads();
  if (t < n_out) {
    float o = bp[t];
    #pragma unroll 8
    for (int k = 0; k < HID; ++k) o = fmaf(ls[0][k] + ls[1][k], Wp[k * n_out + t], o);
    out[g * n_out + t] = o;
  }
}

// ---------------- launch ----------------

extern "C" void kernel_launch(void* const* d_in, const int* in_sizes, int n_in,
                              void* d_out, int out_size, void* d_ws, size_t ws_size,
                              hipStream_t stream) {
  const float* x      = (const float*)d_in[0];
  const int*   ei     = (const int*)d_in[1];
  const int*   batch  = (const int*)d_in[2];
  const float* W_pre  = (const float*)d_in[3];
  const float* b_pre  = (const float*)d_in[4];
  const float* conv_W = (const float*)d_in[5];
  const float* conv_b = (const float*)d_in[6];
  const float* ln_g   = (const float*)d_in[7];
  const float* ln_b   = (const float*)d_in[8];
  const float* W_post = (const float*)d_in[9];
  const float* b_post = (const float*)d_in[10];
  float* out = (float*)d_out;

  const int N = in_sizes[2];          // 50000
  const int E = in_sizes[1] / 2;      // 600000
  const int OUT_DIM = 10;
  const int NG = out_size / OUT_DIM;  // 512

  // workspace carve (all 16B-aligned)
  char* p = (char*)d_ws;
  float* ACC = (float*)p;            p += (size_t)N * HID * 4;   // fp32 running sum
  short* H0  = (short*)p;            p += (size_t)N * HID * 2;   // bf16
  short* B1  = (short*)p;            p += (size_t)N * HID * 2;   // bf16
  short* G   = (short*)p;            p += (size_t)N * HID * 2;   // bf16
  short* Wt  = (short*)p;            p += (size_t)5 * HID * HID * 2;
  float* dinv = (float*)p;           p += (size_t)N * 4;
  int* deg   = (int*)p;              p += (size_t)N * 4;
  int* roff  = (int*)p;              p += (size_t)(N + 4) * 4;
  int* cur   = (int*)p;              p += (size_t)N * 4;
  int* col   = (int*)p;              p += (size_t)E * 4;

  const int* srcp = ei;
  const int* dstp = ei + E;

  int nb256 = (N + 255) / 256;
  int eb256 = (E + 255) / 256;
  int gemm_grid = (N + 127) / 128;
  int agg_grid = (N + 3) / 4;

  prep_w_kernel<<<5 * HID, 64, 0, stream>>>(W_pre, conv_W, Wt);

  zero_ints_kernel<<<nb256, 256, 0, stream>>>(deg, N);
  deg_count_kernel<<<eb256, 256, 0, stream>>>(dstp, E, deg);
  scan_kernel<<<1, 1024, 0, stream>>>(deg, roff, cur, N);
  fill_csr_kernel<<<eb256, 256, 0, stream>>>(srcp, dstp, E, cur, col);
  dinv_kernel<<<nb256, 256, 0, stream>>>(deg, dinv, N);

  // pre MLP: H0 = bf16(x @ W_pre + b_pre)
  gemm_mfma_kernel<true><<<gemm_grid, 256, 0, stream>>>(x, Wt + 0 * 16384, b_pre, nullptr, H0, N);

  // cell 0
  gemm_mfma_kernel<false><<<gemm_grid, 256, 0, stream>>>(H0, Wt + 1 * 16384, nullptr, dinv, G, N);
  agg_ln_kernel<<<agg_grid, 256, 0, stream>>>(G, roff, col, dinv, conv_b + 0 * HID,
                                              ln_g + 0 * HID, ln_b + 0 * HID, B1, ACC, N, 0);
  // cell 1
  gemm_mfma_kernel<false><<<gemm_grid, 256, 0, stream>>>(B1, Wt + 2 * 16384, nullptr, dinv, G, N);
  agg_ln_kernel<<<agg_grid, 256, 0, stream>>>(G, roff, col, dinv, conv_b + 1 * HID,
                                              ln_g + 1 * HID, ln_b + 1 * HID, nullptr, ACC, N, 1);
  // cell 2 (input ACC fp32)
  gemm_mfma_kernel<true><<<gemm_grid, 256, 0, stream>>>(ACC, Wt + 3 * 16384, nullptr, dinv, G, N);
  agg_ln_kernel<<<agg_grid, 256, 0, stream>>>(G, roff, col, dinv, conv_b + 2 * HID,
                                              ln_g + 2 * HID, ln_b + 2 * HID, nullptr, ACC, N, 1);
  // cell 3 (input ACC fp32)
  gemm_mfma_kernel<true><<<gemm_grid, 256, 0, stream>>>(ACC, Wt + 4 * 16384, nullptr, dinv, G, N);
  agg_ln_kernel<<<agg_grid, 256, 0, stream>>>(G, roff, col, dinv, conv_b + 3 * HID,
                                              ln_g + 3 * HID, ln_b + 3 * HID, B1, nullptr, N, 2);

  // pooling + post MLP
  pool_post_kernel<<<NG, 128, 0, stream>>>(B1, batch, N, W_post, b_post, out, OUT_DIM);
}

// Round 3
// 318.967 us; speedup vs baseline: 1.9071x; 1.1706x over previous
//
#include <hip/hip_runtime.h>

#define HID 128
#define LN_EPS 1e-5f

using f32x4 = __attribute__((ext_vector_type(4))) float;
using s16x8 = __attribute__((ext_vector_type(8))) short;

__device__ inline float bl2f(unsigned u) { u <<= 16; return __builtin_bit_cast(float, u); }
__device__ inline float bh2f(unsigned u) { u &= 0xffff0000u; return __builtin_bit_cast(float, u); }
__device__ inline unsigned f2b_bits(float f) {
  unsigned u = __builtin_bit_cast(unsigned, f);
  return (u + 0x7fffu + ((u >> 16) & 1u)) >> 16;  // RNE
}
__device__ inline short f2b(float f) { return (short)f2b_bits(f); }
__device__ inline unsigned pack2(float a, float b) { return f2b_bits(a) | (f2b_bits(b) << 16); }

// ---------------- combined pre-weight: Wc = W_pre @ convW0 (fp32), b' = b_pre @ convW0 ----------------

__global__ __launch_bounds__(128) void prep_comb_kernel(const float* __restrict__ W_pre,
                                                        const float* __restrict__ b_pre,
                                                        const float* __restrict__ convW0,
                                                        float* __restrict__ Wc,
                                                        float* __restrict__ bprime) {
  int m = blockIdx.x;  // 0..127 rows of W_pre; 128 -> bias row
  int t = threadIdx.x;
  const float* arow = (m == HID) ? b_pre : W_pre + (size_t)m * HID;
  float acc = 0.f;
  #pragma unroll 8
  for (int k = 0; k < HID; ++k) acc = fmaf(arow[k], convW0[(size_t)k * HID + t], acc);
  if (m == HID) bprime[t] = acc;
  else Wc[(size_t)m * HID + t] = acc;
}

// ---------------- weight prep: Wt[w][n][k] = bf16(src_w[k][n]) ----------------
// w=0: Wc (combined, fp32 scratch); w=1..3: conv_W[1..3]

__global__ __launch_bounds__(64) void prep_w_kernel(const float* __restrict__ Wc,
                                                    const float* __restrict__ conv_W,
                                                    short* __restrict__ Wt) {
  int b = blockIdx.x;            // 0..511
  int w = b >> 7, n = b & 127;
  const float* W = (w == 0) ? Wc : conv_W + (size_t)w * HID * HID;
  int t = threadIdx.x;           // k = 2t, 2t+1
  float f0 = W[(2 * t) * HID + n];
  float f1 = W[(2 * t + 1) * HID + n];
  ((unsigned*)Wt)[(size_t)(w * HID + n) * 64 + t] = pack2(f0, f1);
}

// ---------------- CSR build (scan-free) ----------------

__global__ void zero_ints_kernel(int* __restrict__ p, int n) {
  int i = blockIdx.x * blockDim.x + threadIdx.x;
  if (i < n) p[i] = 0;
}

__global__ void deg_count_kernel(const int* __restrict__ dst, int E, int* __restrict__ deg) {
  int e = blockIdx.x * blockDim.x + threadIdx.x;
  if (e < E) atomicAdd(&deg[dst[e]], 1);
}

// Per-block scan + single atomic for base; segment order across blocks is irrelevant.
__global__ __launch_bounds__(256) void alloc_kernel(const int* __restrict__ deg,
                                                    int* __restrict__ start,
                                                    int* __restrict__ cur,
                                                    float* __restrict__ dinv,
                                                    int* __restrict__ cnt, int n) {
  __shared__ int wt[4];
  __shared__ int bbase;
  int t = threadIdx.x, lane = t & 63, wid = t >> 6;
  int i = blockIdx.x * 256 + t;
  int d = (i < n) ? deg[i] : 0;
  int x = d;
  #pragma unroll
  for (int off = 1; off < 64; off <<= 1) {
    int u = __shfl_up(x, off, 64);
    if (lane >= off) x += u;
  }
  if (lane == 63) wt[wid] = x;
  __syncthreads();
  if (t == 0) bbase = atomicAdd(cnt, wt[0] + wt[1] + wt[2] + wt[3]);
  __syncthreads();
  int wbase = bbase;
  for (int w = 0; w < wid; ++w) wbase += wt[w];
  int excl = wbase + x - d;
  if (i < n) {
    start[i] = excl;
    cur[i] = excl;
    dinv[i] = rsqrtf((float)(d + 1));
  }
}

__global__ void fill_csr_kernel(const int* __restrict__ src, const int* __restrict__ dst,
                                int E, int* __restrict__ cur, int* __restrict__ col) {
  int e = blockIdx.x * blockDim.x + threadIdx.x;
  if (e < E) {
    int d = dst[e];
    int p = atomicAdd(&cur[d], 1);
    col[p] = src[e];
  }
}

// ---------------- MFMA GEMM: Y[M,128](bf16) = X[M,128] @ Wt^T, epi (acc+bias)*dinv ----------------

template<bool AF32>
__global__ __launch_bounds__(256) void gemm_mfma_kernel(
    const void* __restrict__ Xv, const short* __restrict__ Wt,
    const float* __restrict__ bias, const float* __restrict__ dinv,
    short* __restrict__ Y, int M) {
  __shared__ short lds[4 * 32 * HID];  // 32 KB
  int t = threadIdx.x;
  int wave = t >> 6, l = t & 63;
  int lg = l >> 4, lr = l & 15;
  int mb = blockIdx.x * 128 + wave * 32;

  const f32x4 z4 = {0.f, 0.f, 0.f, 0.f};
  f32x4 acc[2][8];
  #pragma unroll
  for (int i = 0; i < 2; ++i)
    #pragma unroll
    for (int j = 0; j < 8; ++j) acc[i][j] = z4;

  const short* Xb = (const short*)Xv;
  const float* Xf = (const float*)Xv;

  #pragma unroll
  for (int kk = 0; kk < 4; ++kk) {
    int k0 = kk * 32 + lg * 8;
    s16x8 a[2];
    #pragma unroll
    for (int mf = 0; mf < 2; ++mf) {
      int row = mb + mf * 16 + lr;
      s16x8 av = {0, 0, 0, 0, 0, 0, 0, 0};
      if (row < M) {
        if constexpr (AF32) {
          const float4* p = (const float4*)(Xf + (size_t)row * HID + k0);
          float4 x0 = p[0], x1 = p[1];
          av[0] = f2b(x0.x); av[1] = f2b(x0.y); av[2] = f2b(x0.z); av[3] = f2b(x0.w);
          av[4] = f2b(x1.x); av[5] = f2b(x1.y); av[6] = f2b(x1.z); av[7] = f2b(x1.w);
        } else {
          av = *(const s16x8*)(Xb + (size_t)row * HID + k0);
        }
      }
      a[mf] = av;
    }
    #pragma unroll
    for (int nf = 0; nf < 8; ++nf) {
      s16x8 b = *(const s16x8*)(Wt + (size_t)(nf * 16 + lr) * HID + k0);
      acc[0][nf] = __builtin_amdgcn_mfma_f32_16x16x32_bf16(a[0], b, acc[0][nf], 0, 0, 0);
      acc[1][nf] = __builtin_amdgcn_mfma_f32_16x16x32_bf16(a[1], b, acc[1][nf], 0, 0, 0);
    }
  }

  float bv[8];
  #pragma unroll
  for (int nf = 0; nf < 8; ++nf) bv[nf] = bias ? bias[nf * 16 + lr] : 0.f;

  short* wsl = lds + wave * 32 * HID;
  #pragma unroll
  for (int mf = 0; mf < 2; ++mf) {
    #pragma unroll
    for (int r = 0; r < 4; ++r) {
      int ri = mf * 16 + lg * 4 + r;
      int row = mb + ri;
      float dv = 1.f;
      if (dinv && row < M) dv = dinv[row];
      #pragma unroll
      for (int nf = 0; nf < 8; ++nf) {
        float v = (acc[mf][nf][r] + bv[nf]) * dv;
        wsl[ri * HID + nf * 16 + lr] = f2b(v);
      }
    }
  }
  __syncthreads();

  #pragma unroll
  for (int it = 0; it < 8; ++it) {
    int ro = it * 4 + lg;
    int row = mb + ro;
    s16x8 v = *(const s16x8*)(wsl + it * 512 + l * 8);
    if (row < M) *(s16x8*)(Y + (size_t)row * HID + lr * 8) = v;
  }
}

// ---------------- aggregation + LayerNorm + ReLU: one wave per node ----------------
// mode 0: y = val, accum = val;  mode 1: accum += val;  mode 2: y = val.
// accum is bf16 (only ever consumed as a bf16 GEMM A-operand).

__global__ __launch_bounds__(256) void agg_ln_kernel(
    const short* __restrict__ G, const int* __restrict__ start, const int* __restrict__ deg,
    const float* __restrict__ dinv, const float* __restrict__ bias,
    const float* __restrict__ lng, const float* __restrict__ lnb,
    const int* __restrict__ col,
    short* __restrict__ y, short* __restrict__ accum, int N, int mode) {
  int wave = threadIdx.x >> 6, l = threadIdx.x & 63;
  int v = blockIdx.x * 4 + wave;
  if (v >= N) return;

  const unsigned* GR = (const unsigned*)G;  // row v at GR[v*64 + l] -> channels 2l, 2l+1
  unsigned us = GR[(size_t)v * 64 + l];
  float a0 = bl2f(us), a1 = bh2f(us);

  int lo = start[v], hi = lo + deg[v];
  int j = lo;
  for (; j + 7 < hi; j += 8) {
    unsigned u0 = GR[(size_t)col[j + 0] * 64 + l];
    unsigned u1 = GR[(size_t)col[j + 1] * 64 + l];
    unsigned u2 = GR[(size_t)col[j + 2] * 64 + l];
    unsigned u3 = GR[(size_t)col[j + 3] * 64 + l];
    unsigned u4 = GR[(size_t)col[j + 4] * 64 + l];
    unsigned u5 = GR[(size_t)col[j + 5] * 64 + l];
    unsigned u6 = GR[(size_t)col[j + 6] * 64 + l];
    unsigned u7 = GR[(size_t)col[j + 7] * 64 + l];
    a0 += (bl2f(u0) + bl2f(u1)) + (bl2f(u2) + bl2f(u3)) +
          (bl2f(u4) + bl2f(u5)) + (bl2f(u6) + bl2f(u7));
    a1 += (bh2f(u0) + bh2f(u1)) + (bh2f(u2) + bh2f(u3)) +
          (bh2f(u4) + bh2f(u5)) + (bh2f(u6) + bh2f(u7));
  }
  if (j < hi) {
    unsigned u0 =              GR[(size_t)col[j + 0] * 64 + l];
    unsigned u1 = (j + 1 < hi) ? GR[(size_t)col[j + 1] * 64 + l] : 0u;
    unsigned u2 = (j + 2 < hi) ? GR[(size_t)col[j + 2] * 64 + l] : 0u;
    unsigned u3 = (j + 3 < hi) ? GR[(size_t)col[j + 3] * 64 + l] : 0u;
    unsigned u4 = (j + 4 < hi) ? GR[(size_t)col[j + 4] * 64 + l] : 0u;
    unsigned u5 = (j + 5 < hi) ? GR[(size_t)col[j + 5] * 64 + l] : 0u;
    unsigned u6 = (j + 6 < hi) ? GR[(size_t)col[j + 6] * 64 + l] : 0u;
    unsigned u7 = (j + 7 < hi) ? GR[(size_t)col[j + 7] * 64 + l] : 0u;
    a0 += (bl2f(u0) + bl2f(u1)) + (bl2f(u2) + bl2f(u3)) +
          (bl2f(u4) + bl2f(u5)) + (bl2f(u6) + bl2f(u7));
    a1 += (bh2f(u0) + bh2f(u1)) + (bh2f(u2) + bh2f(u3)) +
          (bh2f(u4) + bh2f(u5)) + (bh2f(u6) + bh2f(u7));
  }

  float d = dinv[v];
  float2 bc = *(const float2*)(bias + 2 * l);
  a0 = a0 * d + bc.x;
  a1 = a1 * d + bc.y;

  float s1s = a0 + a1, s2s = a0 * a0 + a1 * a1;
  #pragma unroll
  for (int off = 32; off >= 1; off >>= 1) {
    s1s += __shfl_xor(s1s, off, 64);
    s2s += __shfl_xor(s2s, off, 64);
  }
  float mu = s1s * (1.f / HID);
  float var = s2s * (1.f / HID) - mu * mu;
  float inv = rsqrtf(fmaxf(var, 0.f) + LN_EPS);

  float2 gg = *(const float2*)(lng + 2 * l);
  float2 bb = *(const float2*)(lnb + 2 * l);
  float y0 = fmaxf((a0 - mu) * inv * gg.x + bb.x, 0.f);
  float y1 = fmaxf((a1 - mu) * inv * gg.y + bb.y, 0.f);

  size_t idx = (size_t)v * 64 + l;
  if (mode == 0) {
    ((unsigned*)y)[idx] = pack2(y0, y1);
    ((unsigned*)accum)[idx] = pack2(y0, y1);
  } else if (mode == 1) {
    unsigned o = ((unsigned*)accum)[idx];
    ((unsigned*)accum)[idx] = pack2(bl2f(o) + y0, bh2f(o) + y1);
  } else {
    ((unsigned*)y)[idx] = pack2(y0, y1);
  }
}

// ---------------- pooling + post MLP ----------------

__device__ inline int lower_bound_i(const int* a, int n, int key) {
  int lo = 0, hi = n;
  while (lo < hi) { int m = (lo + hi) >> 1; if (a[m] < key) lo = m + 1; else hi = m; }
  return lo;
}

__global__ __launch_bounds__(128) void pool_post_kernel(
    const short* __restrict__ Yl, const int* __restrict__ batch, int n,
    const float* __restrict__ Wp, const float* __restrict__ bp,
    float* __restrict__ out, int n_out) {
  int g = blockIdx.x, t = threadIdx.x;
  int wave = t >> 6, l = t & 63;
  int lo = lower_bound_i(batch, n, g);
  int hi = lower_bound_i(batch, n, g + 1);
  const unsigned* YR = (const unsigned*)Yl;
  float a0 = 0.f, a1 = 0.f;
  for (int i = lo + wave; i < hi; i += 2) {
    unsigned u = YR[(size_t)i * 64 + l];
    a0 += bl2f(u); a1 += bh2f(u);
  }
  __shared__ float ls[2][HID];
  ls[wave][2 * l] = a0;
  ls[wave][2 * l + 1] = a1;
  __syncthreads();
  if (t < n_out) {
    float o = bp[t];
    #pragma unroll 8
    for (int k = 0; k < HID; ++k) o = fmaf(ls[0][k] + ls[1][k], Wp[k * n_out + t], o);
    out[g * n_out + t] = o;
  }
}

// ---------------- launch ----------------

extern "C" void kernel_launch(void* const* d_in, const int* in_sizes, int n_in,
                              void* d_out, int out_size, void* d_ws, size_t ws_size,
                              hipStream_t stream) {
  const float* x      = (const float*)d_in[0];
  const int*   ei     = (const int*)d_in[1];
  const int*   batch  = (const int*)d_in[2];
  const float* W_pre  = (const float*)d_in[3];
  const float* b_pre  = (const float*)d_in[4];
  const float* conv_W = (const float*)d_in[5];
  const float* conv_b = (const float*)d_in[6];
  const float* ln_g   = (const float*)d_in[7];
  const float* ln_b   = (const float*)d_in[8];
  const float* W_post = (const float*)d_in[9];
  const float* b_post = (const float*)d_in[10];
  float* out = (float*)d_out;

  const int N = in_sizes[2];          // 50000
  const int E = in_sizes[1] / 2;      // 600000
  const int OUT_DIM = 10;
  const int NG = out_size / OUT_DIM;  // 512

  // workspace carve (all 16B-aligned)
  char* p = (char*)d_ws;
  short* ACC = (short*)p;            p += (size_t)N * HID * 2;   // bf16 running sum
  short* B1  = (short*)p;            p += (size_t)N * HID * 2;   // bf16
  short* G   = (short*)p;            p += (size_t)N * HID * 2;   // bf16
  short* Wt  = (short*)p;            p += (size_t)4 * HID * HID * 2;
  float* Wc  = (float*)p;            p += (size_t)HID * HID * 4; // combined pre-weight fp32
  float* bpr = (float*)p;            p += (size_t)HID * 4;
  float* dinv = (float*)p;           p += (size_t)N * 4;
  int* deg   = (int*)p;              p += (size_t)(N + 1) * 4;   // [N] = global counter
  int* startv = (int*)p;             p += (size_t)N * 4;
  int* cur   = (int*)p;              p += (size_t)N * 4;
  int* col   = (int*)p;              p += (size_t)E * 4;
  int* cnt   = deg + N;

  const int* srcp = ei;
  const int* dstp = ei + E;

  int nb256 = (N + 255) / 256;
  int eb256 = (E + 255) / 256;
  int gemm_grid = (N + 127) / 128;
  int agg_grid = (N + 3) / 4;

  // weight prep
  prep_comb_kernel<<<HID + 1, HID, 0, stream>>>(W_pre, b_pre, conv_W, Wc, bpr);
  prep_w_kernel<<<4 * HID, 64, 0, stream>>>(Wc, conv_W, Wt);

  // CSR + dinv (scan-free)
  zero_ints_kernel<<<nb256, 256, 0, stream>>>(deg, N + 1);
  deg_count_kernel<<<eb256, 256, 0, stream>>>(dstp, E, deg);
  alloc_kernel<<<nb256, 256, 0, stream>>>(deg, startv, cur, dinv, cnt, N);
  fill_csr_kernel<<<eb256, 256, 0, stream>>>(srcp, dstp, E, cur, col);

  // cell 0 (pre-MLP folded in): G = dinv*(x@Wc + b')
  gemm_mfma_kernel<true><<<gemm_grid, 256, 0, stream>>>(x, Wt + 0 * 16384, bpr, dinv, G, N);
  agg_ln_kernel<<<agg_grid, 256, 0, stream>>>(G, startv, deg, dinv, conv_b + 0 * HID,
                                              ln_g + 0 * HID, ln_b + 0 * HID, col, B1, ACC, N, 0);
  // cell 1
  gemm_mfma_kernel<false><<<gemm_grid, 256, 0, stream>>>(B1, Wt + 1 * 16384, nullptr, dinv, G, N);
  agg_ln_kernel<<<agg_grid, 256, 0, stream>>>(G, startv, deg, dinv, conv_b + 1 * HID,
                                              ln_g + 1 * HID, ln_b + 1 * HID, col, nullptr, ACC, N, 1);
  // cell 2
  gemm_mfma_kernel<false><<<gemm_grid, 256, 0, stream>>>(ACC, Wt + 2 * 16384, nullptr, dinv, G, N);
  agg_ln_kernel<<<agg_grid, 256, 0, stream>>>(G, startv, deg, dinv, conv_b + 2 * HID,
                                              ln_g + 2 * HID, ln_b + 2 * HID, col, nullptr, ACC, N, 1);
  // cell 3
  gemm_mfma_kernel<false><<<gemm_grid, 256, 0, stream>>>(ACC, Wt + 3 * 16384, nullptr, dinv, G, N);
  agg_ln_kernel<<<agg_grid, 256, 0, stream>>>(G, startv, deg, dinv, conv_b + 3 * HID,
                                              ln_g + 3 * HID, ln_b + 3 * HID, col, B1, nullptr, N, 2);

  // pooling + post MLP
  pool_post_kernel<<<NG, 128, 0, stream>>>(B1, batch, N, W_post, b_post, out, OUT_DIM);
}

// Round 4
// 301.471 us; speedup vs baseline: 2.0178x; 1.0580x over previous
//
#include <hip/hip_runtime.h>

#define HID 128
#define LN_EPS 1e-5f

using f32x4 = __attribute__((ext_vector_type(4))) float;
using s16x8 = __attribute__((ext_vector_type(8))) short;

__device__ inline float bl2f(unsigned u) { u <<= 16; return __builtin_bit_cast(float, u); }
__device__ inline float bh2f(unsigned u) { u &= 0xffff0000u; return __builtin_bit_cast(float, u); }
__device__ inline unsigned f2b_bits(float f) {
  unsigned u = __builtin_bit_cast(unsigned, f);
  return (u + 0x7fffu + ((u >> 16) & 1u)) >> 16;  // RNE
}
__device__ inline short f2b(float f) { return (short)f2b_bits(f); }
__device__ inline unsigned pack2(float a, float b) { return f2b_bits(a) | (f2b_bits(b) << 16); }

__device__ inline void addu4(const uint4 u, float a[8]) {
  a[0] += bl2f(u.x); a[1] += bh2f(u.x);
  a[2] += bl2f(u.y); a[3] += bh2f(u.y);
  a[4] += bl2f(u.z); a[5] += bh2f(u.z);
  a[6] += bl2f(u.w); a[7] += bh2f(u.w);
}

// ---------------- combined pre-weight: Wc = W_pre @ convW0 (fp32), b' = b_pre @ convW0 ----------------

__global__ __launch_bounds__(128) void prep_comb_kernel(const float* __restrict__ W_pre,
                                                        const float* __restrict__ b_pre,
                                                        const float* __restrict__ convW0,
                                                        float* __restrict__ Wc,
                                                        float* __restrict__ bprime) {
  int m = blockIdx.x;  // 0..127 rows of W_pre; 128 -> bias row
  int t = threadIdx.x;
  const float* arow = (m == HID) ? b_pre : W_pre + (size_t)m * HID;
  float acc = 0.f;
  #pragma unroll 8
  for (int k = 0; k < HID; ++k) acc = fmaf(arow[k], convW0[(size_t)k * HID + t], acc);
  if (m == HID) bprime[t] = acc;
  else Wc[(size_t)m * HID + t] = acc;
}

// ---------------- weight prep: Wt[w][n][k] = bf16(src_w[k][n]) ----------------

__global__ __launch_bounds__(64) void prep_w_kernel(const float* __restrict__ Wc,
                                                    const float* __restrict__ conv_W,
                                                    short* __restrict__ Wt) {
  int b = blockIdx.x;            // 0..511
  int w = b >> 7, n = b & 127;
  const float* W = (w == 0) ? Wc : conv_W + (size_t)w * HID * HID;
  int t = threadIdx.x;           // k = 2t, 2t+1
  float f0 = W[(2 * t) * HID + n];
  float f1 = W[(2 * t + 1) * HID + n];
  ((unsigned*)Wt)[(size_t)(w * HID + n) * 64 + t] = pack2(f0, f1);
}

// ---------------- CSR build (scan-free) ----------------

__global__ void zero_ints_kernel(int* __restrict__ p, int n) {
  int i = blockIdx.x * blockDim.x + threadIdx.x;
  if (i < n) p[i] = 0;
}

__global__ void deg_count_kernel(const int* __restrict__ dst, int E, int* __restrict__ deg) {
  int e = blockIdx.x * blockDim.x + threadIdx.x;
  if (e < E) atomicAdd(&deg[dst[e]], 1);
}

__global__ __launch_bounds__(256) void alloc_kernel(const int* __restrict__ deg,
                                                    int* __restrict__ start,
                                                    int* __restrict__ cur,
                                                    float* __restrict__ dinv,
                                                    int* __restrict__ cnt, int n) {
  __shared__ int wt[4];
  __shared__ int bbase;
  int t = threadIdx.x, lane = t & 63, wid = t >> 6;
  int i = blockIdx.x * 256 + t;
  int d = (i < n) ? deg[i] : 0;
  int x = d;
  #pragma unroll
  for (int off = 1; off < 64; off <<= 1) {
    int u = __shfl_up(x, off, 64);
    if (lane >= off) x += u;
  }
  if (lane == 63) wt[wid] = x;
  __syncthreads();
  if (t == 0) bbase = atomicAdd(cnt, wt[0] + wt[1] + wt[2] + wt[3]);
  __syncthreads();
  int wbase = bbase;
  for (int w = 0; w < wid; ++w) wbase += wt[w];
  int excl = wbase + x - d;
  if (i < n) {
    start[i] = excl;
    cur[i] = excl;
    dinv[i] = rsqrtf((float)(d + 1));
  }
}

__global__ void fill_csr_kernel(const int* __restrict__ src, const int* __restrict__ dst,
                                int E, int* __restrict__ cur, int* __restrict__ col) {
  int e = blockIdx.x * blockDim.x + threadIdx.x;
  if (e < E) {
    int d = dst[e];
    int p = atomicAdd(&cur[d], 1);
    col[p] = src[e];
  }
}

// ---------------- MFMA GEMM: Y[M,128](bf16) = X[M,128] @ Wt^T, epi (acc+bias)*dinv ----------------

template<bool AF32>
__global__ __launch_bounds__(256) void gemm_mfma_kernel(
    const void* __restrict__ Xv, const short* __restrict__ Wt,
    const float* __restrict__ bias, const float* __restrict__ dinv,
    short* __restrict__ Y, int M) {
  __shared__ short lds[4 * 32 * HID];  // 32 KB
  int t = threadIdx.x;
  int wave = t >> 6, l = t & 63;
  int lg = l >> 4, lr = l & 15;
  int mb = blockIdx.x * 128 + wave * 32;

  const f32x4 z4 = {0.f, 0.f, 0.f, 0.f};
  f32x4 acc[2][8];
  #pragma unroll
  for (int i = 0; i < 2; ++i)
    #pragma unroll
    for (int j = 0; j < 8; ++j) acc[i][j] = z4;

  const short* Xb = (const short*)Xv;
  const float* Xf = (const float*)Xv;

  #pragma unroll
  for (int kk = 0; kk < 4; ++kk) {
    int k0 = kk * 32 + lg * 8;
    s16x8 a[2];
    #pragma unroll
    for (int mf = 0; mf < 2; ++mf) {
      int row = mb + mf * 16 + lr;
      s16x8 av = {0, 0, 0, 0, 0, 0, 0, 0};
      if (row < M) {
        if constexpr (AF32) {
          const float4* p = (const float4*)(Xf + (size_t)row * HID + k0);
          float4 x0 = p[0], x1 = p[1];
          av[0] = f2b(x0.x); av[1] = f2b(x0.y); av[2] = f2b(x0.z); av[3] = f2b(x0.w);
          av[4] = f2b(x1.x); av[5] = f2b(x1.y); av[6] = f2b(x1.z); av[7] = f2b(x1.w);
        } else {
          av = *(const s16x8*)(Xb + (size_t)row * HID + k0);
        }
      }
      a[mf] = av;
    }
    #pragma unroll
    for (int nf = 0; nf < 8; ++nf) {
      s16x8 b = *(const s16x8*)(Wt + (size_t)(nf * 16 + lr) * HID + k0);
      acc[0][nf] = __builtin_amdgcn_mfma_f32_16x16x32_bf16(a[0], b, acc[0][nf], 0, 0, 0);
      acc[1][nf] = __builtin_amdgcn_mfma_f32_16x16x32_bf16(a[1], b, acc[1][nf], 0, 0, 0);
    }
  }

  float bv[8];
  #pragma unroll
  for (int nf = 0; nf < 8; ++nf) bv[nf] = bias ? bias[nf * 16 + lr] : 0.f;

  short* wsl = lds + wave * 32 * HID;
  #pragma unroll
  for (int mf = 0; mf < 2; ++mf) {
    #pragma unroll
    for (int r = 0; r < 4; ++r) {
      int ri = mf * 16 + lg * 4 + r;
      int row = mb + ri;
      float dv = 1.f;
      if (dinv && row < M) dv = dinv[row];
      #pragma unroll
      for (int nf = 0; nf < 8; ++nf) {
        float v = (acc[mf][nf][r] + bv[nf]) * dv;
        wsl[ri * HID + nf * 16 + lr] = f2b(v);
      }
    }
  }
  __syncthreads();

  #pragma unroll
  for (int it = 0; it < 8; ++it) {
    int ro = it * 4 + lg;
    int row = mb + ro;
    s16x8 v = *(const s16x8*)(wsl + it * 512 + l * 8);
    if (row < M) *(s16x8*)(Y + (size_t)row * HID + lr * 8) = v;
  }
}

// ---------------- aggregation + LayerNorm + ReLU ----------------
// One wave per node. 16B/lane gathers: 16 lanes cover one 256B row, the wave's
// 4 sub-groups handle 4 neighbors per VMEM instruction; 2 in flight per iter.
// mode 0: y = val, accum = val;  mode 1: accum += val;  mode 2: y = val.

__global__ __launch_bounds__(256) void agg_ln_kernel(
    const short* __restrict__ G, const int* __restrict__ start, const int* __restrict__ deg,
    const float* __restrict__ dinv, const float* __restrict__ bias,
    const float* __restrict__ lng, const float* __restrict__ lnb,
    const int* __restrict__ col,
    short* __restrict__ y, short* __restrict__ accum, int N, int mode) {
  int wave = threadIdx.x >> 6, l = threadIdx.x & 63;
  int v = blockIdx.x * 4 + wave;
  if (v >= N) return;
  int lr = l & 15, sub = l >> 4;

  const uint4* GR = (const uint4*)G;  // row r = GR[r*16 + q]; lane's q = lr (channels 8lr..8lr+7)
  float a[8] = {0.f, 0.f, 0.f, 0.f, 0.f, 0.f, 0.f, 0.f};

  if (sub == 0) addu4(GR[(size_t)v * 16 + lr], a);  // self loop (counted once)

  int lo = start[v], hi = lo + deg[v];
  int j = lo;
  for (; j + 8 <= hi; j += 8) {
    int c0 = col[j + sub];
    int c1 = col[j + 4 + sub];
    uint4 u0 = GR[(size_t)c0 * 16 + lr];
    uint4 u1 = GR[(size_t)c1 * 16 + lr];
    addu4(u0, a);
    addu4(u1, a);
  }
  for (; j < hi; j += 4) {
    if (j + sub < hi) addu4(GR[(size_t)col[j + sub] * 16 + lr], a);
  }

  // reduce across the 4 sub-groups (lanes l, l^16, l^32, l^48)
  #pragma unroll
  for (int i = 0; i < 8; ++i) {
    a[i] += __shfl_xor(a[i], 16, 64);
    a[i] += __shfl_xor(a[i], 32, 64);
  }

  float d = dinv[v];
  const float4* bp4 = (const float4*)(bias + 8 * lr);
  float4 bc0 = bp4[0], bc1 = bp4[1];
  float bb[8] = {bc0.x, bc0.y, bc0.z, bc0.w, bc1.x, bc1.y, bc1.z, bc1.w};
  #pragma unroll
  for (int i = 0; i < 8; ++i) a[i] = fmaf(a[i], d, bb[i]);

  float s1 = 0.f, s2 = 0.f;
  #pragma unroll
  for (int i = 0; i < 8; ++i) { s1 += a[i]; s2 = fmaf(a[i], a[i], s2); }
  #pragma unroll
  for (int off = 1; off <= 8; off <<= 1) {
    s1 += __shfl_xor(s1, off, 64);
    s2 += __shfl_xor(s2, off, 64);
  }
  float mu = s1 * (1.f / HID);
  float var = s2 * (1.f / HID) - mu * mu;
  float inv = rsqrtf(fmaxf(var, 0.f) + LN_EPS);

  const float4* gp4 = (const float4*)(lng + 8 * lr);
  const float4* pp4 = (const float4*)(lnb + 8 * lr);
  float4 g0 = gp4[0], g1 = gp4[1], p0 = pp4[0], p1 = pp4[1];
  float gg[8] = {g0.x, g0.y, g0.z, g0.w, g1.x, g1.y, g1.z, g1.w};
  float pb[8] = {p0.x, p0.y, p0.z, p0.w, p1.x, p1.y, p1.z, p1.w};
  float yv[8];
  #pragma unroll
  for (int i = 0; i < 8; ++i) yv[i] = fmaxf(fmaf((a[i] - mu) * inv, gg[i], pb[i]), 0.f);

  if (sub == 0) {
    uint4 o;
    o.x = pack2(yv[0], yv[1]); o.y = pack2(yv[2], yv[3]);
    o.z = pack2(yv[4], yv[5]); o.w = pack2(yv[6], yv[7]);
    uint4* Yw = (uint4*)y;
    uint4* Aw = (uint4*)accum;
    size_t idx = (size_t)v * 16 + lr;
    if (mode == 0) { Yw[idx] = o; Aw[idx] = o; }
    else if (mode == 1) {
      uint4 po = Aw[idx];
      uint4 q;
      q.x = pack2(bl2f(po.x) + yv[0], bh2f(po.x) + yv[1]);
      q.y = pack2(bl2f(po.y) + yv[2], bh2f(po.y) + yv[3]);
      q.z = pack2(bl2f(po.z) + yv[4], bh2f(po.z) + yv[5]);
      q.w = pack2(bl2f(po.w) + yv[6], bh2f(po.w) + yv[7]);
      Aw[idx] = q;
    } else {
      Yw[idx] = o;
    }
  }
}

// ---------------- pooling + post MLP ----------------

__device__ inline int lower_bound_i(const int* a, int n, int key) {
  int lo = 0, hi = n;
  while (lo < hi) { int m = (lo + hi) >> 1; if (a[m] < key) lo = m + 1; else hi = m; }
  return lo;
}

__global__ __launch_bounds__(128) void pool_post_kernel(
    const short* __restrict__ Yl, const int* __restrict__ batch, int n,
    const float* __restrict__ Wp, const float* __restrict__ bp,
    float* __restrict__ out, int n_out) {
  int g = blockIdx.x, t = threadIdx.x;
  int wave = t >> 6;
  int lr = t & 15, slot = t >> 4;  // 8 row-slots x 16 lanes
  int lo = lower_bound_i(batch, n, g);
  int hi = lower_bound_i(batch, n, g + 1);
  const uint4* YR = (const uint4*)Yl;
  float a[8] = {0.f, 0.f, 0.f, 0.f, 0.f, 0.f, 0.f, 0.f};
  for (int r = lo + slot; r < hi; r += 8) addu4(YR[(size_t)r * 16 + lr], a);
  // reduce across sub-groups within each wave
  #pragma unroll
  for (int i = 0; i < 8; ++i) {
    a[i] += __shfl_xor(a[i], 16, 64);
    a[i] += __shfl_xor(a[i], 32, 64);
  }
  __shared__ float ls[2][HID];
  if ((slot & 3) == 0) {
    #pragma unroll
    for (int i = 0; i < 8; ++i) ls[wave][8 * lr + i] = a[i];
  }
  __syncthreads();
  if (t < n_out) {
    float o = bp[t];
    #pragma unroll 8
    for (int k = 0; k < HID; ++k) o = fmaf(ls[0][k] + ls[1][k], Wp[k * n_out + t], o);
    out[g * n_out + t] = o;
  }
}

// ---------------- launch ----------------

extern "C" void kernel_launch(void* const* d_in, const int* in_sizes, int n_in,
                              void* d_out, int out_size, void* d_ws, size_t ws_size,
                              hipStream_t stream) {
  const float* x      = (const float*)d_in[0];
  const int*   ei     = (const int*)d_in[1];
  const int*   batch  = (const int*)d_in[2];
  const float* W_pre  = (const float*)d_in[3];
  const float* b_pre  = (const float*)d_in[4];
  const float* conv_W = (const float*)d_in[5];
  const float* conv_b = (const float*)d_in[6];
  const float* ln_g   = (const float*)d_in[7];
  const float* ln_b   = (const float*)d_in[8];
  const float* W_post = (const float*)d_in[9];
  const float* b_post = (const float*)d_in[10];
  float* out = (float*)d_out;

  const int N = in_sizes[2];          // 50000
  const int E = in_sizes[1] / 2;      // 600000
  const int OUT_DIM = 10;
  const int NG = out_size / OUT_DIM;  // 512

  // workspace carve (all 16B-aligned)
  char* p = (char*)d_ws;
  short* ACC = (short*)p;            p += (size_t)N * HID * 2;   // bf16 running sum
  short* B1  = (short*)p;            p += (size_t)N * HID * 2;   // bf16
  short* G   = (short*)p;            p += (size_t)N * HID * 2;   // bf16
  short* Wt  = (short*)p;            p += (size_t)4 * HID * HID * 2;
  float* Wc  = (float*)p;            p += (size_t)HID * HID * 4; // combined pre-weight fp32
  float* bpr = (float*)p;            p += (size_t)HID * 4;
  float* dinv = (float*)p;           p += (size_t)N * 4;
  int* deg   = (int*)p;              p += (size_t)(N + 1) * 4;   // [N] = global counter
  int* startv = (int*)p;             p += (size_t)N * 4;
  int* cur   = (int*)p;              p += (size_t)N * 4;
  int* col   = (int*)p;              p += (size_t)E * 4;
  int* cnt   = deg + N;

  const int* srcp = ei;
  const int* dstp = ei + E;

  int nb256 = (N + 255) / 256;
  int eb256 = (E + 255) / 256;
  int gemm_grid = (N + 127) / 128;
  int agg_grid = (N + 3) / 4;

  // weight prep
  prep_comb_kernel<<<HID + 1, HID, 0, stream>>>(W_pre, b_pre, conv_W, Wc, bpr);
  prep_w_kernel<<<4 * HID, 64, 0, stream>>>(Wc, conv_W, Wt);

  // CSR + dinv (scan-free)
  zero_ints_kernel<<<nb256, 256, 0, stream>>>(deg, N + 1);
  deg_count_kernel<<<eb256, 256, 0, stream>>>(dstp, E, deg);
  alloc_kernel<<<nb256, 256, 0, stream>>>(deg, startv, cur, dinv, cnt, N);
  fill_csr_kernel<<<eb256, 256, 0, stream>>>(srcp, dstp, E, cur, col);

  // cell 0 (pre-MLP folded in): G = dinv*(x@Wc + b')
  gemm_mfma_kernel<true><<<gemm_grid, 256, 0, stream>>>(x, Wt + 0 * 16384, bpr, dinv, G, N);
  agg_ln_kernel<<<agg_grid, 256, 0, stream>>>(G, startv, deg, dinv, conv_b + 0 * HID,
                                              ln_g + 0 * HID, ln_b + 0 * HID, col, B1, ACC, N, 0);
  // cell 1
  gemm_mfma_kernel<false><<<gemm_grid, 256, 0, stream>>>(B1, Wt + 1 * 16384, nullptr, dinv, G, N);
  agg_ln_kernel<<<agg_grid, 256, 0, stream>>>(G, startv, deg, dinv, conv_b + 1 * HID,
                                              ln_g + 1 * HID, ln_b + 1 * HID, col, nullptr, ACC, N, 1);
  // cell 2
  gemm_mfma_kernel<false><<<gemm_grid, 256, 0, stream>>>(ACC, Wt + 2 * 16384, nullptr, dinv, G, N);
  agg_ln_kernel<<<agg_grid, 256, 0, stream>>>(G, startv, deg, dinv, conv_b + 2 * HID,
                                              ln_g + 2 * HID, ln_b + 2 * HID, col, nullptr, ACC, N, 1);
  // cell 3
  gemm_mfma_kernel<false><<<gemm_grid, 256, 0, stream>>>(ACC, Wt + 3 * 16384, nullptr, dinv, G, N);
  agg_ln_kernel<<<agg_grid, 256, 0, stream>>>(G, startv, deg, dinv, conv_b + 3 * HID,
                                              ln_g + 3 * HID, ln_b + 3 * HID, col, B1, nullptr, N, 2);

  // pooling + post MLP
  pool_post_kernel<<<NG, 128, 0, stream>>>(B1, batch, N, W_post, b_post, out, OUT_DIM);
}